// Round 6
// baseline (370.844 us; speedup 1.0000x reference)
//
#include <hip/hip_runtime.h>
#include <hip/hip_cooperative_groups.h>
#include <math.h>

namespace cg = cooperative_groups;

// Problem constants (B,K,N,M) = (32,128,128,256)
#define Bb 32
#define Kk 128
#define Nn 128
#define Mm 256
#define EPS2 0.01f      // EPSILON^2
#define LAMBDA_S 0.1f
#define LR 0.01f
#define BN_EPS_C 1e-5f

#define SWZ(c) (((c) & 14) | (((c) & 1) << 4) | (((c) >> 4) & 1))

// ---------------------------------------------------------------------------
// Phase bodies as __device__ functions; LB = per-block LDS scratch.
// ---------------------------------------------------------------------------

// BN over (B,M) for channel n. Uses LB[0..7].
__device__ __forceinline__ void ph_bn(const float* __restrict__ x,
                                      float* __restrict__ xn, float* LB,
                                      int n, int t) {
  float s = 0.f, s2 = 0.f;
  #pragma unroll 4
  for (int b = 0; b < Bb; ++b) {
    float v = x[(size_t)b * (Nn * Mm) + n * Mm + t];
    s += v;
    s2 += v * v;
  }
  #pragma unroll
  for (int o = 32; o > 0; o >>= 1) {
    s += __shfl_down(s, o, 64);
    s2 += __shfl_down(s2, o, 64);
  }
  float* rs = LB;
  float* rs2 = LB + 4;
  if ((t & 63) == 0) { rs[t >> 6] = s; rs2[t >> 6] = s2; }
  __syncthreads();
  float S = rs[0] + rs[1] + rs[2] + rs[3];
  float S2 = rs2[0] + rs2[1] + rs2[2] + rs2[3];
  float mean = S * (1.0f / (Bb * Mm));
  float var = S2 * (1.0f / (Bb * Mm)) - mean * mean;
  float rstd = 1.0f / sqrtf(var + BN_EPS_C);
  #pragma unroll 4
  for (int b = 0; b < Bb; ++b) {
    size_t idx = (size_t)b * (Nn * Mm) + n * Mm + t;
    xn[idx] = (x[idx] - mean) * rstd;
  }
}

// Psum = sum_k P[k], 64 block-units.
__device__ __forceinline__ void ph_psum(const float* __restrict__ P,
                                        float* __restrict__ Psum, int bxx, int t) {
  int e = bxx * 256 + t;
  float s = 0.f;
  #pragma unroll 8
  for (int k = 0; k < Kk; ++k) s += P[(size_t)k * 16384 + e];
  Psum[e] = s;
}

// Blocked Gauss-Jordan inverse (nb=16), 8x8 register tiles. Uses LB[0..4163].
__device__ __forceinline__ void ph_k3(const float* __restrict__ P,
                                      const float* __restrict__ Psum,
                                      const float* __restrict__ cnt,
                                      float* __restrict__ C, float* LB,
                                      int blk, int t) {
  float* Mt = LB;            // 16*132 = 2112
  float* Rb = LB + 2112;     // 16*128 = 2048
  float* redc = LB + 4160;   // 4
  int tx = t & 15, ty = t >> 4;

  float cv = cnt[t & 127];
  float sr = cv;
  #pragma unroll
  for (int o = 32; o > 0; o >>= 1) sr += __shfl_down(sr, o, 64);
  if ((t & 63) == 0) redc[t >> 6] = sr;
  __syncthreads();
  float total = redc[0] + redc[1];
  bool has = total > 1e-6f;
  float av;
  if (blk < 128) {
    float c = cnt[blk];
    float bk = (c != 0.0f) ? 1.0f : 0.0f;
    float cfix = c + (1.0f - bk);
    av = (float)Nn / (cfix * EPS2) * bk;
  } else {
    av = has ? ((float)Nn / (EPS2 * total)) : 0.0f;
  }
  const float* src = (blk < 128) ? (P + (size_t)blk * 16384) : Psum;

  float a[8][8];
  #pragma unroll
  for (int i = 0; i < 8; ++i) {
    int row = ty * 8 + i;
    float4 p0 = *(const float4*)&src[row * 128 + tx * 8];
    float4 p1 = *(const float4*)&src[row * 128 + tx * 8 + 4];
    a[i][0] = av * p0.x; a[i][1] = av * p0.y; a[i][2] = av * p0.z; a[i][3] = av * p0.w;
    a[i][4] = av * p1.x; a[i][5] = av * p1.y; a[i][6] = av * p1.z; a[i][7] = av * p1.w;
    if (tx == ty) a[i][i] += 1.0f;
  }

  for (int kb = 0; kb < 8; ++kb) {
    int k0 = kb * 16;
    if ((ty >> 1) == kb) {
      int d = ty & 1;
      #pragma unroll
      for (int i = 0; i < 8; ++i) {
        *(float4*)&Rb[(d * 8 + i) * 128 + SWZ(2 * tx) * 4] =
            make_float4(a[i][0], a[i][1], a[i][2], a[i][3]);
        *(float4*)&Rb[(d * 8 + i) * 128 + SWZ(2 * tx + 1) * 4] =
            make_float4(a[i][4], a[i][5], a[i][6], a[i][7]);
      }
    }
    if ((tx >> 1) == kb) {
      int dh = tx & 1;
      #pragma unroll
      for (int i = 0; i < 8; ++i)
        #pragma unroll
        for (int j = 0; j < 8; ++j)
          Mt[(dh * 8 + j) * 132 + ty * 8 + i] = a[i][j];
    }
    __syncthreads();

    if (t < 64) {
      int l = t;
      float m[2][16];
      #pragma unroll
      for (int d = 0; d < 2; ++d)
        #pragma unroll
        for (int j = 0; j < 16; ++j)
          m[d][j] = Mt[j * 132 + 2 * l + d];
      #pragma unroll
      for (int q = 0; q < 16; ++q) {
        int lq = (k0 + q) >> 1;
        float pr[16];
        #pragma unroll
        for (int j = 0; j < 16; ++j) pr[j] = __shfl(m[q & 1][j], lq, 64);
        float pinv = 1.0f / pr[q];
        #pragma unroll
        for (int d = 0; d < 2; ++d) {
          float f = m[d][q];
          bool isp = (2 * l + d == k0 + q);
          float g = isp ? (1.0f - pinv) : f * pinv;
          #pragma unroll
          for (int j = 0; j < 16; ++j) m[d][j] = fmaf(-g, pr[j], m[d][j]);
          m[d][q] = isp ? pinv : -g;
        }
      }
      #pragma unroll
      for (int d = 0; d < 2; ++d)
        #pragma unroll
        for (int j = 0; j < 16; ++j)
          Mt[j * 132 + 2 * l + d] = m[d][j];
    }
    __syncthreads();

    if ((ty >> 1) == kb) {
      #pragma unroll
      for (int i = 0; i < 8; ++i)
        #pragma unroll
        for (int j = 0; j < 8; ++j) a[i][j] = 0.0f;
    }
    #pragma unroll
    for (int q = 0; q < 16; ++q) {
      float4 m0 = *(const float4*)&Mt[q * 132 + ty * 8];
      float4 m1 = *(const float4*)&Mt[q * 132 + ty * 8 + 4];
      float4 r0 = *(const float4*)&Rb[q * 128 + SWZ(2 * tx) * 4];
      float4 r1 = *(const float4*)&Rb[q * 128 + SWZ(2 * tx + 1) * 4];
      float mq[8] = {m0.x, m0.y, m0.z, m0.w, m1.x, m1.y, m1.z, m1.w};
      float rq[8] = {r0.x, r0.y, r0.z, r0.w, r1.x, r1.y, r1.z, r1.w};
      #pragma unroll
      for (int i = 0; i < 8; ++i)
        #pragma unroll
        for (int j = 0; j < 8; ++j)
          a[i][j] = fmaf(mq[i], rq[j], a[i][j]);
    }
    if ((tx >> 1) == kb) {
      int dh = tx & 1;
      #pragma unroll
      for (int j = 0; j < 8; ++j) {
        float4 v0 = *(const float4*)&Mt[(dh * 8 + j) * 132 + ty * 8];
        float4 v1 = *(const float4*)&Mt[(dh * 8 + j) * 132 + ty * 8 + 4];
        a[0][j] = v0.x; a[1][j] = v0.y; a[2][j] = v0.z; a[3][j] = v0.w;
        a[4][j] = v1.x; a[5][j] = v1.y; a[6][j] = v1.z; a[7][j] = v1.w;
      }
    }
    __syncthreads();
  }

  float* dst = C + (size_t)blk * 16384;
  #pragma unroll
  for (int i = 0; i < 8; ++i) {
    int row = ty * 8 + i;
    float4 v0 = make_float4(av * a[i][0], av * a[i][1], av * a[i][2], av * a[i][3]);
    float4 v1 = make_float4(av * a[i][4], av * a[i][5], av * a[i][6], av * a[i][7]);
    *(float4*)&dst[row * 128 + tx * 8] = v0;
    *(float4*)&dst[row * 128 + tx * 8 + 4] = v1;
  }
}

// S_b = xn_b xn_b^T, 64 block-units (b = bxx>>1, col-half = bxx&1). LB: 128*65.
__device__ __forceinline__ void ph_S(const float* __restrict__ xn,
                                     float* __restrict__ S, float* LB,
                                     int bxx, int t) {
  int b = bxx >> 1;
  int jbase = (bxx & 1) * 64;
  float* X = LB;
  int tx = t & 15, ty = t >> 4;
  float acc[8][4] = {};
  for (int mc = 0; mc < Mm; mc += 64) {
    __syncthreads();
    for (int c = 0; c < 32; ++c) {
      int e = c * 256 + t;
      int i = e >> 6, mm = e & 63;
      X[i * 65 + mm] = xn[(size_t)b * (Nn * Mm) + i * Mm + mc + mm];
    }
    __syncthreads();
    for (int mm = 0; mm < 64; ++mm) {
      float ai[8], bj[4];
      #pragma unroll
      for (int q = 0; q < 8; ++q) ai[q] = X[(ty * 8 + q) * 65 + mm];
      #pragma unroll
      for (int q = 0; q < 4; ++q) bj[q] = X[(jbase + tx * 4 + q) * 65 + mm];
      #pragma unroll
      for (int qi = 0; qi < 8; ++qi)
        #pragma unroll
        for (int qj = 0; qj < 4; ++qj)
          acc[qi][qj] = fmaf(ai[qi], bj[qj], acc[qi][qj]);
    }
  }
  float* dst = S + (size_t)b * 16384;
  #pragma unroll
  for (int qi = 0; qi < 8; ++qi) {
    float4 v = make_float4(acc[qi][0], acc[qi][1], acc[qi][2], acc[qi][3]);
    *(float4*)&dst[(ty * 8 + qi) * 128 + jbase + tx * 4] = v;
  }
}

// G_k = c_k^T c_k with full 64 KB matrix in LDS, 8x8 outputs/thread.
__device__ __forceinline__ void ph_gram(const float* __restrict__ C,
                                        float* __restrict__ G, float* LB,
                                        int k, int t) {
  const float* src = C + (size_t)k * 16384;
  for (int c = 0; c < 64; ++c) LB[c * 256 + t] = src[c * 256 + t];
  __syncthreads();
  int tx = t & 15, ty = t >> 4;
  int i0 = ty * 8, j0 = tx * 8;
  float acc[8][8] = {};
  for (int l = 0; l < 128; ++l) {
    float ai[8], bj[8];
    *(float4*)&ai[0] = *(const float4*)&LB[l * 128 + i0];
    *(float4*)&ai[4] = *(const float4*)&LB[l * 128 + i0 + 4];
    *(float4*)&bj[0] = *(const float4*)&LB[l * 128 + j0];
    *(float4*)&bj[4] = *(const float4*)&LB[l * 128 + j0 + 4];
    #pragma unroll
    for (int qi = 0; qi < 8; ++qi)
      #pragma unroll
      for (int qj = 0; qj < 8; ++qj)
        acc[qi][qj] = fmaf(ai[qi], bj[qj], acc[qi][qj]);
  }
  float* dst = G + (size_t)k * 16384;
  #pragma unroll
  for (int qi = 0; qi < 8; ++qi) {
    float4 v0 = make_float4(acc[qi][0], acc[qi][1], acc[qi][2], acc[qi][3]);
    float4 v1 = make_float4(acc[qi][4], acc[qi][5], acc[qi][6], acc[qi][7]);
    *(float4*)&dst[(i0 + qi) * 128 + j0] = v0;
    *(float4*)&dst[(i0 + qi) * 128 + j0 + 4] = v1;
  }
}

// part[c][b][k] over inner chunk c. LB: 128*65 + 32*65 = 10400.
__device__ __forceinline__ void ph_k6(const float* __restrict__ G,
                                      const float* __restrict__ S,
                                      float* __restrict__ part, float* LB,
                                      int c, int t) {
  float* Gp = LB;            // 128*65
  float* Sp = LB + 128 * 65; // 32*65
  int off = c * 64;
  for (int q = 0; q < 32; ++q) {
    int e = q * 256 + t;
    int k = e >> 6, jj = e & 63;
    Gp[k * 65 + jj] = G[(size_t)k * 16384 + off + jj];
  }
  for (int q = 0; q < 8; ++q) {
    int e = q * 256 + t;
    int b = e >> 6, jj = e & 63;
    Sp[b * 65 + jj] = S[(size_t)b * 16384 + off + jj];
  }
  __syncthreads();
  int tk = t & 15, tb = t >> 4;
  float acc[2][8] = {};
  for (int jj = 0; jj < 64; ++jj) {
    float sv0 = Sp[(tb * 2) * 65 + jj];
    float sv1 = Sp[(tb * 2 + 1) * 65 + jj];
    float gv[8];
    #pragma unroll
    for (int q = 0; q < 8; ++q) gv[q] = Gp[(tk + 16 * q) * 65 + jj];
    #pragma unroll
    for (int q = 0; q < 8; ++q) {
      acc[0][q] = fmaf(sv0, gv[q], acc[0][q]);
      acc[1][q] = fmaf(sv1, gv[q], acc[1][q]);
    }
  }
  float* pout = part + (size_t)c * 4096;
  #pragma unroll
  for (int bb = 0; bb < 2; ++bb)
    #pragma unroll
    for (int q = 0; q < 8; ++q)
      pout[(tb * 2 + bb) * 128 + tk + 16 * q] = acc[bb][q];
}

// norms -> rescale -> softmax -> wT[k][b]. LB: 268 floats.
__device__ __forceinline__ void ph_k7(const float* __restrict__ part,
                                      const float* __restrict__ cnt,
                                      float* __restrict__ wT, float* LB,
                                      int b, int t) {
  float* sh = LB;           // 256
  float* redt = LB + 256;   // 4
  float* red = LB + 260;    // 4
  float* red2 = LB + 264;   // 4
  int k = t & 127, h = t >> 7;
  float s = 0.f;
  #pragma unroll 8
  for (int c = h * 128; c < h * 128 + 128; ++c)
    s += part[(size_t)c * 4096 + b * 128 + k];
  sh[t] = s;
  __syncthreads();
  float norm2 = sh[k] + sh[k + 128];
  float norm = sqrtf(fmaxf(norm2, 0.0f));
  float cv = cnt[k];
  float tt = cv;
  #pragma unroll
  for (int o = 32; o > 0; o >>= 1) tt += __shfl_down(tt, o, 64);
  if ((t & 63) == 0) redt[t >> 6] = tt;
  float r = norm;
  #pragma unroll
  for (int o = 32; o > 0; o >>= 1) r += __shfl_down(r, o, 64);
  if ((t & 63) == 0) red[t >> 6] = r;
  __syncthreads();
  float total = redt[0] + redt[1];
  float sumn = 0.5f * (red[0] + red[1] + red[2] + red[3]);
  float nr = 10.0f * norm / fmaxf(sumn, 1e-30f);
  float ex = expf(-LAMBDA_S * nr);
  float r2 = ex;
  #pragma unroll
  for (int o = 32; o > 0; o >>= 1) r2 += __shfl_down(r2, o, 64);
  if ((t & 63) == 0) red2[t >> 6] = r2;
  __syncthreads();
  float sume = 0.5f * (red2[0] + red2[1] + red2[2] + red2[3]);
  float bk = (cv != 0.0f) ? 1.0f : 0.0f;
  float pi = (ex / sume) * bk;
  float gama = (total > 1e-6f) ? (cv / total) : 0.0f;
  if (h == 0) wT[k * 32 + b] = gama * pi;
}

// F[b] = e - sum_k w[b][k]*c_k ; 256 block-units (e-block = bx&63, b0 = (bx>>6)*8).
__device__ __forceinline__ void ph_k8(const float* __restrict__ C,
                                      const float* __restrict__ E,
                                      const float* __restrict__ wT,
                                      float* __restrict__ F, int bx, int t) {
  int e = (bx & 63) * 256 + t;
  int b0 = (bx >> 6) * 8;
  float acc[8];
  float ev = E[e];
  #pragma unroll
  for (int b = 0; b < 8; ++b) acc[b] = ev;
  for (int k = 0; k < 128; ++k) {
    float cv = C[(size_t)k * 16384 + e];
    const float* wk = wT + k * 32 + b0;
    #pragma unroll
    for (int b = 0; b < 8; ++b) acc[b] = fmaf(-wk[b], cv, acc[b]);
  }
  #pragma unroll
  for (int b = 0; b < 8; ++b) F[(size_t)(b0 + b) * 16384 + e] = acc[b];
}

// out[b] = xn[b] + LR * F[b] @ xn[b]; 256 block-units (b=bx>>3, mq=(bx&7)>>1,
// ih=bx&1). LB: 2*64*65 = 8320.
__device__ __forceinline__ void ph_k9(const float* __restrict__ F,
                                      const float* __restrict__ xn,
                                      float* __restrict__ out, float* LB,
                                      int bx, int t) {
  int b = bx >> 3, y = bx & 7;
  int mq = y >> 1, ih = y & 1;
  float* Ft = LB;            // 64 x 65
  float* Xt = LB + 64 * 65;  // 64 x 65
  int tx = t & 15, ty = t >> 4;
  float acc[4][4] = {};
  for (int jc = 0; jc < 128; jc += 64) {
    __syncthreads();
    for (int q = 0; q < 16; ++q) {
      int e = q * 256 + t;
      int i = e >> 6, jj = e & 63;
      Ft[i * 65 + jj] = F[(size_t)b * 16384 + (ih * 64 + i) * 128 + jc + jj];
    }
    for (int q = 0; q < 16; ++q) {
      int e = q * 256 + t;
      int jj = e >> 6, mm = e & 63;
      Xt[jj * 65 + mm] = xn[(size_t)b * (Nn * Mm) + (jc + jj) * Mm + mq * 64 + mm];
    }
    __syncthreads();
    for (int jj = 0; jj < 64; ++jj) {
      float fi[4], xm[4];
      #pragma unroll
      for (int q = 0; q < 4; ++q) fi[q] = Ft[(ty * 4 + q) * 65 + jj];
      #pragma unroll
      for (int q = 0; q < 4; ++q) xm[q] = Xt[jj * 65 + tx * 4 + q];
      #pragma unroll
      for (int qi = 0; qi < 4; ++qi)
        #pragma unroll
        for (int qj = 0; qj < 4; ++qj)
          acc[qi][qj] = fmaf(fi[qi], xm[qj], acc[qi][qj]);
    }
  }
  int i0 = ih * 64 + ty * 4, m0 = mq * 64 + tx * 4;
  #pragma unroll
  for (int qi = 0; qi < 4; ++qi) {
    float4 xv = *(const float4*)&xn[(size_t)b * (Nn * Mm) + (i0 + qi) * Mm + m0];
    float4 o;
    o.x = fmaf(LR, acc[qi][0], xv.x);
    o.y = fmaf(LR, acc[qi][1], xv.y);
    o.z = fmaf(LR, acc[qi][2], xv.z);
    o.w = fmaf(LR, acc[qi][3], xv.w);
    *(float4*)&out[(size_t)b * (Nn * Mm) + (i0 + qi) * Mm + m0] = o;
  }
}

// ---------------------------------------------------------------------------
// Fused cooperative kernel: all phases, grid.sync between them. S overlaps k3.
__global__ __launch_bounds__(256, 1) void fused_all(
    const float* __restrict__ x, const float* __restrict__ P,
    const float* __restrict__ cnt, float* __restrict__ out,
    float* __restrict__ xn, float* __restrict__ C, float* __restrict__ G,
    float* __restrict__ S, float* __restrict__ part, float* __restrict__ wT,
    float* __restrict__ Psum, float* __restrict__ F) {
  cg::grid_group grid = cg::this_grid();
  __shared__ __align__(16) float LB[16384];  // 64 KB, carved per phase
  int bx = blockIdx.x;
  int t = threadIdx.x;

  if (bx < 128) ph_bn(x, xn, LB, bx, t);
  else if (bx < 192) ph_psum(P, Psum, bx - 128, t);
  grid.sync();

  if (bx < 129) ph_k3(P, Psum, cnt, C, LB, bx, t);
  else if (bx < 193) ph_S(xn, S, LB, bx - 129, t);  // overlaps the invert
  grid.sync();

  if (bx < 128) ph_gram(C, G, LB, bx, t);
  grid.sync();

  ph_k6(G, S, part, LB, bx, t);
  grid.sync();

  if (bx < 32) ph_k7(part, cnt, wT, LB, bx, t);
  grid.sync();

  ph_k8(C, C + (size_t)128 * 16384, wT, F, bx, t);
  grid.sync();

  if (bx < 128) ph_k9(F, xn, out, LB, bx * 2, t),
                ph_k9(F, xn, out, LB, bx * 2 + 1, t);
}

// ---------------------------------------------------------------------------
// Fallback standalone kernels (used only if cooperative launch fails).
__global__ void kA_bn_psum(const float* x, const float* P, float* xn, float* Psum) {
  __shared__ __align__(16) float LBs[8];
  if (blockIdx.x < 128) ph_bn(x, xn, LBs, blockIdx.x, threadIdx.x);
  else ph_psum(P, Psum, blockIdx.x - 128, threadIdx.x);
}
__global__ __launch_bounds__(256, 1) void k3_k(const float* P, const float* Psum,
                                               const float* cnt, float* C) {
  __shared__ __align__(16) float LBs[4164];
  ph_k3(P, Psum, cnt, C, LBs, blockIdx.x, threadIdx.x);
}
__global__ __launch_bounds__(256, 1) void k45_k(const float* C, const float* xn,
                                                float* G, float* S) {
  __shared__ __align__(16) float LBs[16384];
  if (blockIdx.x < 128) ph_gram(C, G, LBs, blockIdx.x, threadIdx.x);
  else ph_S(xn, S, LBs, blockIdx.x - 128, threadIdx.x);
}
__global__ __launch_bounds__(256, 1) void k6_k(const float* G, const float* S,
                                               float* part) {
  __shared__ __align__(16) float LBs[10400];
  ph_k6(G, S, part, LBs, blockIdx.x, threadIdx.x);
}
__global__ void k7_k(const float* part, const float* cnt, float* wT) {
  __shared__ __align__(16) float LBs[268];
  ph_k7(part, cnt, wT, LBs, blockIdx.x, threadIdx.x);
}
__global__ __launch_bounds__(256, 1) void k8_k(const float* C, const float* E,
                                               const float* wT, float* F) {
  ph_k8(C, E, wT, F, blockIdx.x, threadIdx.x);
}
__global__ __launch_bounds__(256, 1) void k9_k(const float* F, const float* xn,
                                               float* out) {
  __shared__ __align__(16) float LBs[8320];
  ph_k9(F, xn, out, LBs, blockIdx.x, threadIdx.x);
}

// ---------------------------------------------------------------------------
extern "C" void kernel_launch(void* const* d_in, const int* in_sizes, int n_in,
                              void* d_out, int out_size, void* d_ws, size_t ws_size,
                              hipStream_t stream) {
  const float* x = (const float*)d_in[0];     // (32,128,256)
  const float* P = (const float*)d_in[1];     // (128,128,128) EC_proto
  const float* cnt = (const float*)d_in[2];   // (128,)
  float* out = (float*)d_out;

  float* ws = (float*)d_ws;
  float* xn = ws;                               // 1048576
  float* C = xn + 1048576;                      // 129*16384 (c_k; slot 128 = e)
  float* G = C + 2113536;                       // 2097152
  float* S = G + 2097152;                       // 524288
  float* part = S + 524288;                     // 1048576
  float* F = part + 1048576;                    // 524288
  float* wT = F + 524288;                       // 4096
  float* Psum = wT + 4096;                      // 16384
  size_t need_bytes = (size_t)((Psum + 16384) - ws) * sizeof(float);
  if (ws_size < need_bytes) return;  // ~29.5 MB required

  void* args[] = {(void*)&x, (void*)&P, (void*)&cnt, (void*)&out,
                  (void*)&xn, (void*)&C, (void*)&G, (void*)&S,
                  (void*)&part, (void*)&wT, (void*)&Psum, (void*)&F};
  hipError_t err = hipLaunchCooperativeKernel((void*)fused_all, dim3(256),
                                              dim3(256), args, 0, stream);
  if (err != hipSuccess) {
    // Fallback: 7 standalone launches (same math).
    hipLaunchKernelGGL(kA_bn_psum, dim3(192), dim3(256), 0, stream, x, P, xn, Psum);
    hipLaunchKernelGGL(k3_k, dim3(129), dim3(256), 0, stream, P, Psum, cnt, C);
    hipLaunchKernelGGL(k45_k, dim3(192), dim3(256), 0, stream, C, xn, G, S);
    hipLaunchKernelGGL(k6_k, dim3(256), dim3(256), 0, stream, G, S, part);
    hipLaunchKernelGGL(k7_k, dim3(32), dim3(256), 0, stream, part, cnt, wT);
    hipLaunchKernelGGL(k8_k, dim3(256), dim3(256), 0, stream, C,
                       C + (size_t)128 * 16384, wT, F);
    hipLaunchKernelGGL(k9_k, dim3(256), dim3(256), 0, stream, F, xn, out);
  }
}

// Round 7
// 177.458 us; speedup vs baseline: 2.0898x; 2.0898x over previous
//
#include <hip/hip_runtime.h>
#include <math.h>

// Problem constants (B,K,N,M) = (32,128,128,256)
#define Bb 32
#define Kk 128
#define Nn 128
#define Mm 256
#define EPS2 0.01f      // EPSILON^2
#define LAMBDA_S 0.1f
#define LR 0.01f
#define BN_EPS_C 1e-5f

#define SWZ(c) (((c) & 14) | (((c) & 1) << 4) | (((c) >> 4) & 1))

// ---------------------------------------------------------------------------
// kA: fused BatchNorm (blocks 0..127) + Psum=sum_k P[k] (blocks 128..191).
__global__ void kA_bn_psum(const float* __restrict__ x, const float* __restrict__ P,
                           float* __restrict__ xn, float* __restrict__ Psum) {
  int t = threadIdx.x;
  if (blockIdx.x < 128) {
    int n = blockIdx.x;
    float s = 0.f, s2 = 0.f;
    #pragma unroll 4
    for (int b = 0; b < Bb; ++b) {
      float v = x[(size_t)b * (Nn * Mm) + n * Mm + t];
      s += v;
      s2 += v * v;
    }
    #pragma unroll
    for (int o = 32; o > 0; o >>= 1) {
      s += __shfl_down(s, o, 64);
      s2 += __shfl_down(s2, o, 64);
    }
    __shared__ float rs[4], rs2[4];
    if ((t & 63) == 0) { rs[t >> 6] = s; rs2[t >> 6] = s2; }
    __syncthreads();
    float S = rs[0] + rs[1] + rs[2] + rs[3];
    float S2 = rs2[0] + rs2[1] + rs2[2] + rs2[3];
    float mean = S * (1.0f / (Bb * Mm));
    float var = S2 * (1.0f / (Bb * Mm)) - mean * mean;
    float rstd = 1.0f / sqrtf(var + BN_EPS_C);
    #pragma unroll 4
    for (int b = 0; b < Bb; ++b) {
      size_t idx = (size_t)b * (Nn * Mm) + n * Mm + t;
      xn[idx] = (x[idx] - mean) * rstd;
    }
  } else {
    int e = (blockIdx.x - 128) * 256 + t;
    float s = 0.f;
    #pragma unroll 8
    for (int k = 0; k < Kk; ++k) s += P[(size_t)k * 16384 + e];
    Psum[e] = s;
  }
}

// ---------------------------------------------------------------------------
// k3S: blocks 0..128 = blocked Gauss-Jordan inverse (nb=16, 8x8 reg tiles);
// blocks 129..192 = S_b = xn_b xn_b^T (independent of k3 -> free overlap).
// grid 193, block 256. Shared LDS buffer 8448 floats (33 KB).
__global__ __launch_bounds__(256, 1) void k3S(
    const float* __restrict__ P, const float* __restrict__ Psum,
    const float* __restrict__ cnt, float* __restrict__ C,
    const float* __restrict__ xn, float* __restrict__ S) {
  __shared__ __align__(16) float LB[8448];
  int bx = blockIdx.x;
  int t = threadIdx.x;

  if (bx < 129) {
    float* Mt = LB;            // 16*132 = 2112
    float* Rb = LB + 2112;     // 16*128 = 2048
    float* redc = LB + 4160;   // 4
    int blk = bx;
    int tx = t & 15, ty = t >> 4;

    float cv = cnt[t & 127];
    float sr = cv;
    #pragma unroll
    for (int o = 32; o > 0; o >>= 1) sr += __shfl_down(sr, o, 64);
    if ((t & 63) == 0) redc[t >> 6] = sr;
    __syncthreads();
    float total = redc[0] + redc[1];
    bool has = total > 1e-6f;
    float av;
    if (blk < 128) {
      float c = cnt[blk];
      float bk = (c != 0.0f) ? 1.0f : 0.0f;
      float cfix = c + (1.0f - bk);
      av = (float)Nn / (cfix * EPS2) * bk;
    } else {
      av = has ? ((float)Nn / (EPS2 * total)) : 0.0f;
    }
    const float* src = (blk < 128) ? (P + (size_t)blk * 16384) : Psum;

    float a[8][8];
    #pragma unroll
    for (int i = 0; i < 8; ++i) {
      int row = ty * 8 + i;
      float4 p0 = *(const float4*)&src[row * 128 + tx * 8];
      float4 p1 = *(const float4*)&src[row * 128 + tx * 8 + 4];
      a[i][0] = av * p0.x; a[i][1] = av * p0.y; a[i][2] = av * p0.z; a[i][3] = av * p0.w;
      a[i][4] = av * p1.x; a[i][5] = av * p1.y; a[i][6] = av * p1.z; a[i][7] = av * p1.w;
      if (tx == ty) a[i][i] += 1.0f;
    }

    for (int kb = 0; kb < 8; ++kb) {
      int k0 = kb * 16;
      if ((ty >> 1) == kb) {          // R dump (swizzled, conflict-free)
        int d = ty & 1;
        #pragma unroll
        for (int i = 0; i < 8; ++i) {
          *(float4*)&Rb[(d * 8 + i) * 128 + SWZ(2 * tx) * 4] =
              make_float4(a[i][0], a[i][1], a[i][2], a[i][3]);
          *(float4*)&Rb[(d * 8 + i) * 128 + SWZ(2 * tx + 1) * 4] =
              make_float4(a[i][4], a[i][5], a[i][6], a[i][7]);
        }
      }
      if ((tx >> 1) == kb) {          // M dump (transposed)
        int dh = tx & 1;
        #pragma unroll
        for (int i = 0; i < 8; ++i)
          #pragma unroll
          for (int j = 0; j < 8; ++j)
            Mt[(dh * 8 + j) * 132 + ty * 8 + i] = a[i][j];
      }
      __syncthreads();

      if (t < 64) {                   // wave 0 factors the panel
        int l = t;
        float m[2][16];
        #pragma unroll
        for (int d = 0; d < 2; ++d)
          #pragma unroll
          for (int j = 0; j < 16; ++j)
            m[d][j] = Mt[j * 132 + 2 * l + d];
        #pragma unroll
        for (int q = 0; q < 16; ++q) {
          int lq = (k0 + q) >> 1;
          float pr[16];
          #pragma unroll
          for (int j = 0; j < 16; ++j) pr[j] = __shfl(m[q & 1][j], lq, 64);
          float pinv = 1.0f / pr[q];
          #pragma unroll
          for (int d = 0; d < 2; ++d) {
            float f = m[d][q];
            bool isp = (2 * l + d == k0 + q);
            float g = isp ? (1.0f - pinv) : f * pinv;
            #pragma unroll
            for (int j = 0; j < 16; ++j) m[d][j] = fmaf(-g, pr[j], m[d][j]);
            m[d][q] = isp ? pinv : -g;
          }
        }
        #pragma unroll
        for (int d = 0; d < 2; ++d)
          #pragma unroll
          for (int j = 0; j < 16; ++j)
            Mt[j * 132 + 2 * l + d] = m[d][j];
      }
      __syncthreads();

      if ((ty >> 1) == kb) {          // rank-16 trailing update
        #pragma unroll
        for (int i = 0; i < 8; ++i)
          #pragma unroll
          for (int j = 0; j < 8; ++j) a[i][j] = 0.0f;
      }
      #pragma unroll
      for (int q = 0; q < 16; ++q) {
        float4 m0 = *(const float4*)&Mt[q * 132 + ty * 8];
        float4 m1 = *(const float4*)&Mt[q * 132 + ty * 8 + 4];
        float4 r0 = *(const float4*)&Rb[q * 128 + SWZ(2 * tx) * 4];
        float4 r1 = *(const float4*)&Rb[q * 128 + SWZ(2 * tx + 1) * 4];
        float mq[8] = {m0.x, m0.y, m0.z, m0.w, m1.x, m1.y, m1.z, m1.w};
        float rq[8] = {r0.x, r0.y, r0.z, r0.w, r1.x, r1.y, r1.z, r1.w};
        #pragma unroll
        for (int i = 0; i < 8; ++i)
          #pragma unroll
          for (int j = 0; j < 8; ++j)
            a[i][j] = fmaf(mq[i], rq[j], a[i][j]);
      }
      if ((tx >> 1) == kb) {          // panel cols reload M
        int dh = tx & 1;
        #pragma unroll
        for (int j = 0; j < 8; ++j) {
          float4 v0 = *(const float4*)&Mt[(dh * 8 + j) * 132 + ty * 8];
          float4 v1 = *(const float4*)&Mt[(dh * 8 + j) * 132 + ty * 8 + 4];
          a[0][j] = v0.x; a[1][j] = v0.y; a[2][j] = v0.z; a[3][j] = v0.w;
          a[4][j] = v1.x; a[5][j] = v1.y; a[6][j] = v1.z; a[7][j] = v1.w;
        }
      }
      __syncthreads();
    }

    float* dst = C + (size_t)blk * 16384;
    #pragma unroll
    for (int i = 0; i < 8; ++i) {
      int row = ty * 8 + i;
      float4 v0 = make_float4(av * a[i][0], av * a[i][1], av * a[i][2], av * a[i][3]);
      float4 v1 = make_float4(av * a[i][4], av * a[i][5], av * a[i][6], av * a[i][7]);
      *(float4*)&dst[row * 128 + tx * 8] = v0;
      *(float4*)&dst[row * 128 + tx * 8 + 4] = v1;
    }
  } else {
    // ---- S branch: S_b = xn_b xn_b^T (b = bxx>>1, col-half = bxx&1) ----
    int bxx = bx - 129;
    int b = bxx >> 1;
    int jbase = (bxx & 1) * 64;
    float* X = LB;  // 128*65 = 8320 floats
    int tx = t & 15, ty = t >> 4;
    float acc[8][4] = {};
    for (int mc = 0; mc < Mm; mc += 64) {
      __syncthreads();
      for (int c = 0; c < 32; ++c) {
        int e = c * 256 + t;
        int i = e >> 6, mm = e & 63;
        X[i * 65 + mm] = xn[(size_t)b * (Nn * Mm) + i * Mm + mc + mm];
      }
      __syncthreads();
      for (int mm = 0; mm < 64; ++mm) {
        float ai[8], bj[4];
        #pragma unroll
        for (int q = 0; q < 8; ++q) ai[q] = X[(ty * 8 + q) * 65 + mm];
        #pragma unroll
        for (int q = 0; q < 4; ++q) bj[q] = X[(jbase + tx * 4 + q) * 65 + mm];
        #pragma unroll
        for (int qi = 0; qi < 8; ++qi)
          #pragma unroll
          for (int qj = 0; qj < 4; ++qj)
            acc[qi][qj] = fmaf(ai[qi], bj[qj], acc[qi][qj]);
      }
    }
    float* dst = S + (size_t)b * 16384;
    #pragma unroll
    for (int qi = 0; qi < 8; ++qi) {
      float4 v = make_float4(acc[qi][0], acc[qi][1], acc[qi][2], acc[qi][3]);
      *(float4*)&dst[(ty * 8 + qi) * 128 + jbase + tx * 4] = v;
    }
  }
}

// ---------------------------------------------------------------------------
// gram: G_k = c_k^T c_k, 2 blocks per k (row-halves) -> 256 blocks on 256 CUs.
// Full c_k (64 KB) in LDS; per-thread 8x4 tile; c symmetric so row-l reads
// serve as column vectors. grid 256, block 256.
__global__ __launch_bounds__(256, 1) void gram_k(const float* __restrict__ C,
                                                 float* __restrict__ G) {
  __shared__ __align__(16) float LB[128 * 128];  // 64 KB
  int k = blockIdx.x >> 1, half = blockIdx.x & 1;
  int t = threadIdx.x;
  const float* src = C + (size_t)k * 16384;
  for (int c = 0; c < 64; ++c) LB[c * 256 + t] = src[c * 256 + t];
  __syncthreads();
  int tx = t & 31, ty = t >> 5;          // 8 x 32 thread map
  int i0 = half * 64 + ty * 8, j0 = tx * 4;
  float acc[8][4] = {};
  for (int l = 0; l < 128; ++l) {
    float ai[8], bj[4];
    *(float4*)&ai[0] = *(const float4*)&LB[l * 128 + i0];
    *(float4*)&ai[4] = *(const float4*)&LB[l * 128 + i0 + 4];
    *(float4*)&bj[0] = *(const float4*)&LB[l * 128 + j0];
    #pragma unroll
    for (int qi = 0; qi < 8; ++qi)
      #pragma unroll
      for (int qj = 0; qj < 4; ++qj)
        acc[qi][qj] = fmaf(ai[qi], bj[qj], acc[qi][qj]);
  }
  float* dst = G + (size_t)k * 16384;
  #pragma unroll
  for (int qi = 0; qi < 8; ++qi)
    *(float4*)&dst[(i0 + qi) * 128 + j0] =
        make_float4(acc[qi][0], acc[qi][1], acc[qi][2], acc[qi][3]);
}

// ---------------------------------------------------------------------------
// k6 v2 (vectorized LDS): part[c][b][k] = sum over chunk c of G[k][.]*S[b][.].
// Pad-68 rows keep float4 alignment; jj unrolled x4 -> b128 LDS reads.
// grid 256, block 256.
__global__ __launch_bounds__(256, 1) void k6_k(const float* __restrict__ G,
                                               const float* __restrict__ S,
                                               float* __restrict__ part) {
  __shared__ __align__(16) float Gp[128 * 68];  // 34.8 KB
  __shared__ __align__(16) float Sp[32 * 68];   // 8.7 KB
  int c = blockIdx.x;
  int t = threadIdx.x;
  int off = c * 64;
  #pragma unroll
  for (int q = 0; q < 8; ++q) {               // 2048 float4 of G-chunk
    int e = q * 256 + t;
    int k = e >> 4, j4 = e & 15;
    *(float4*)&Gp[k * 68 + j4 * 4] = *(const float4*)&G[(size_t)k * 16384 + off + j4 * 4];
  }
  #pragma unroll
  for (int q = 0; q < 2; ++q) {               // 512 float4 of S-chunk
    int e = q * 256 + t;
    int b = e >> 4, j4 = e & 15;
    *(float4*)&Sp[b * 68 + j4 * 4] = *(const float4*)&S[(size_t)b * 16384 + off + j4 * 4];
  }
  __syncthreads();
  int tk = t & 15, tb = t >> 4;               // k = tk + 16q, b = tb*2 + bb
  float acc[2][8] = {};
  for (int j4 = 0; j4 < 16; ++j4) {
    float4 sv0 = *(const float4*)&Sp[(tb * 2) * 68 + j4 * 4];
    float4 sv1 = *(const float4*)&Sp[(tb * 2 + 1) * 68 + j4 * 4];
    float4 gv[8];
    #pragma unroll
    for (int q = 0; q < 8; ++q) gv[q] = *(const float4*)&Gp[(tk + 16 * q) * 68 + j4 * 4];
    #pragma unroll
    for (int q = 0; q < 8; ++q) {
      acc[0][q] = fmaf(sv0.x, gv[q].x, acc[0][q]);
      acc[0][q] = fmaf(sv0.y, gv[q].y, acc[0][q]);
      acc[0][q] = fmaf(sv0.z, gv[q].z, acc[0][q]);
      acc[0][q] = fmaf(sv0.w, gv[q].w, acc[0][q]);
      acc[1][q] = fmaf(sv1.x, gv[q].x, acc[1][q]);
      acc[1][q] = fmaf(sv1.y, gv[q].y, acc[1][q]);
      acc[1][q] = fmaf(sv1.z, gv[q].z, acc[1][q]);
      acc[1][q] = fmaf(sv1.w, gv[q].w, acc[1][q]);
    }
  }
  float* pout = part + (size_t)c * 4096;
  #pragma unroll
  for (int bb = 0; bb < 2; ++bb)
    #pragma unroll
    for (int q = 0; q < 8; ++q)
      pout[(tb * 2 + bb) * 128 + tk + 16 * q] = acc[bb][q];
}

// ---------------------------------------------------------------------------
// k7: partial-reduce -> norm -> rescale -> softmax -> wT[k][b]. grid 32.
__global__ void k7_k(const float* __restrict__ part,
                     const float* __restrict__ cnt, float* __restrict__ wT) {
  int b = blockIdx.x;
  int t = threadIdx.x;
  int k = t & 127, h = t >> 7;
  float s = 0.f;
  #pragma unroll 8
  for (int c = h * 128; c < h * 128 + 128; ++c)
    s += part[(size_t)c * 4096 + b * 128 + k];
  __shared__ float sh[256];
  sh[t] = s;
  __syncthreads();
  float norm2 = sh[k] + sh[k + 128];
  float norm = sqrtf(fmaxf(norm2, 0.0f));
  float cv = cnt[k];
  float tt = cv;
  #pragma unroll
  for (int o = 32; o > 0; o >>= 1) tt += __shfl_down(tt, o, 64);
  __shared__ float redt[4];
  if ((t & 63) == 0) redt[t >> 6] = tt;
  float r = norm;
  #pragma unroll
  for (int o = 32; o > 0; o >>= 1) r += __shfl_down(r, o, 64);
  __shared__ float red[4];
  if ((t & 63) == 0) red[t >> 6] = r;
  __syncthreads();
  float total = redt[0] + redt[1];
  float sumn = 0.5f * (red[0] + red[1] + red[2] + red[3]);
  float nr = 10.0f * norm / fmaxf(sumn, 1e-30f);
  float ex = expf(-LAMBDA_S * nr);
  float r2 = ex;
  #pragma unroll
  for (int o = 32; o > 0; o >>= 1) r2 += __shfl_down(r2, o, 64);
  __shared__ float red2[4];
  if ((t & 63) == 0) red2[t >> 6] = r2;
  __syncthreads();
  float sume = 0.5f * (red2[0] + red2[1] + red2[2] + red2[3]);
  float bk = (cv != 0.0f) ? 1.0f : 0.0f;
  float pi = (ex / sume) * bk;
  float gama = (total > 1e-6f) ? (cv / total) : 0.0f;
  if (h == 0) wT[k * 32 + b] = gama * pi;
}

// ---------------------------------------------------------------------------
// k8: F[b] = e - sum_k w[b][k]*c_k. grid (64,4), block 256.
__global__ __launch_bounds__(256, 1) void k8_k(const float* __restrict__ C,
                                               const float* __restrict__ E,
                                               const float* __restrict__ wT,
                                               float* __restrict__ F) {
  int e = blockIdx.x * 256 + threadIdx.x;
  int b0 = blockIdx.y * 8;
  float acc[8];
  float ev = E[e];
  #pragma unroll
  for (int b = 0; b < 8; ++b) acc[b] = ev;
  for (int k = 0; k < 128; ++k) {
    float cv = C[(size_t)k * 16384 + e];
    const float* wk = wT + k * 32 + b0;
    #pragma unroll
    for (int b = 0; b < 8; ++b) acc[b] = fmaf(-wk[b], cv, acc[b]);
  }
  #pragma unroll
  for (int b = 0; b < 8; ++b) F[(size_t)(b0 + b) * 16384 + e] = acc[b];
}

// ---------------------------------------------------------------------------
// k9 v3 (vectorized LDS, 256 blocks): out[b] = xn[b] + LR * F[b] @ xn[b].
// bx -> (b = bx>>3, mq = (bx&7)>>1, ih = bx&1): 64x64 output tile.
// Pad-68 rows; jj unrolled x4 -> b128 LDS reads. grid 256, block 256.
__global__ __launch_bounds__(256, 1) void k9_k(const float* __restrict__ F,
                                               const float* __restrict__ xn,
                                               float* __restrict__ out) {
  int bx = blockIdx.x;
  int b = bx >> 3, y = bx & 7;
  int mq = y >> 1, ih = y & 1;
  __shared__ __align__(16) float Ft[64 * 68];  // 17.4 KB
  __shared__ __align__(16) float Xt[64 * 68];  // 17.4 KB
  int t = threadIdx.x;
  int tx = t & 15, ty = t >> 4;
  float acc[4][4] = {};
  for (int jc = 0; jc < 128; jc += 64) {
    __syncthreads();
    #pragma unroll
    for (int q = 0; q < 4; ++q) {       // 1024 float4 of F half-rows
      int e = q * 256 + t;
      int i = e >> 4, j4 = e & 15;
      *(float4*)&Ft[i * 68 + j4 * 4] =
          *(const float4*)&F[(size_t)b * 16384 + (ih * 64 + i) * 128 + jc + j4 * 4];
    }
    #pragma unroll
    for (int q = 0; q < 4; ++q) {       // 1024 float4 of X rows
      int e = q * 256 + t;
      int jj = e >> 4, m4 = e & 15;
      *(float4*)&Xt[jj * 68 + m4 * 4] =
          *(const float4*)&xn[(size_t)b * (Nn * Mm) + (jc + jj) * Mm + mq * 64 + m4 * 4];
    }
    __syncthreads();
    for (int j4 = 0; j4 < 16; ++j4) {
      float4 fi[4], xm[4];
      #pragma unroll
      for (int r = 0; r < 4; ++r)
        fi[r] = *(const float4*)&Ft[(ty * 4 + r) * 68 + j4 * 4];
      #pragma unroll
      for (int r = 0; r < 4; ++r)
        xm[r] = *(const float4*)&Xt[(j4 * 4 + r) * 68 + tx * 4];
      #pragma unroll
      for (int qi = 0; qi < 4; ++qi) {
        #pragma unroll
        for (int qm = 0; qm < 4; ++qm) {
          float xv = ((const float*)&xm[0])[qm];
          acc[qi][qm] = fmaf(fi[qi].x, xv, acc[qi][qm]);
          xv = ((const float*)&xm[1])[qm];
          acc[qi][qm] = fmaf(fi[qi].y, xv, acc[qi][qm]);
          xv = ((const float*)&xm[2])[qm];
          acc[qi][qm] = fmaf(fi[qi].z, xv, acc[qi][qm]);
          xv = ((const float*)&xm[3])[qm];
          acc[qi][qm] = fmaf(fi[qi].w, xv, acc[qi][qm]);
        }
      }
    }
  }
  int i0 = ih * 64 + ty * 4, m0 = mq * 64 + tx * 4;
  #pragma unroll
  for (int qi = 0; qi < 4; ++qi) {
    float4 xv = *(const float4*)&xn[(size_t)b * (Nn * Mm) + (i0 + qi) * Mm + m0];
    float4 o;
    o.x = fmaf(LR, acc[qi][0], xv.x);
    o.y = fmaf(LR, acc[qi][1], xv.y);
    o.z = fmaf(LR, acc[qi][2], xv.z);
    o.w = fmaf(LR, acc[qi][3], xv.w);
    *(float4*)&out[(size_t)b * (Nn * Mm) + (i0 + qi) * Mm + m0] = o;
  }
}

// ---------------------------------------------------------------------------
extern "C" void kernel_launch(void* const* d_in, const int* in_sizes, int n_in,
                              void* d_out, int out_size, void* d_ws, size_t ws_size,
                              hipStream_t stream) {
  const float* x = (const float*)d_in[0];     // (32,128,256)
  const float* P = (const float*)d_in[1];     // (128,128,128) EC_proto
  const float* cnt = (const float*)d_in[2];   // (128,)
  float* out = (float*)d_out;

  float* ws = (float*)d_ws;
  float* xn = ws;                               // 1048576
  float* C = xn + 1048576;                      // 129*16384 (c_k; slot 128 = e)
  float* G = C + 2113536;                       // 2097152
  float* S = G + 2097152;                       // 524288
  float* part = S + 524288;                     // 1048576
  float* F = part + 1048576;                    // 524288
  float* wT = F + 524288;                       // 4096
  float* Psum = wT + 4096;                      // 16384
  size_t need_bytes = (size_t)((Psum + 16384) - ws) * sizeof(float);
  if (ws_size < need_bytes) return;  // ~29.5 MB required

  hipLaunchKernelGGL(kA_bn_psum, dim3(192), dim3(256), 0, stream, x, P, xn, Psum);
  hipLaunchKernelGGL(k3S, dim3(193), dim3(256), 0, stream, P, Psum, cnt, C, xn, S);
  hipLaunchKernelGGL(gram_k, dim3(256), dim3(256), 0, stream, C, G);
  hipLaunchKernelGGL(k6_k, dim3(256), dim3(256), 0, stream, G, S, part);
  hipLaunchKernelGGL(k7_k, dim3(32), dim3(256), 0, stream, part, cnt, wT);
  hipLaunchKernelGGL(k8_k, dim3(64, 4), dim3(256), 0, stream, C,
                     C + (size_t)128 * 16384, wT, F);
  hipLaunchKernelGGL(k9_k, dim3(256), dim3(256), 0, stream, F, xn, out);
}